// Round 4
// baseline (94.834 us; speedup 1.0000x reference)
//
#include <hip/hip_runtime.h>
#include <stdint.h>

#define KCODES  1024
#define CDIM    64
#define SPATIAL 32768
#define NPOS    65536
#define NEL     4194304

// d_out layout (floats), outputs concatenated in reference return order
#define OUT_Q    0
#define OUT_LOSS 4194304
#define OUT_IDX  4194305
#define OUT_SUM  4259841
#define OUT_EMB  4260097

// ws: 8 chunks x {hi frags 16KB | lo frags 16KB | -0.5*||e||^2 512B}
#define REC_BYTES 33280
#define BPOS 64            // positions per block

typedef _Float16 half8 __attribute__((ext_vector_type(8)));
typedef float    f32x4 __attribute__((ext_vector_type(4)));

// ---- prep: fragment-swizzle codebook, zero loss/sum, emb passthrough (64 blocks) ----
__global__ void prep_emb(const float* __restrict__ emb, char* __restrict__ ws,
                         float* __restrict__ out) {
    int gt = blockIdx.x * 256 + threadIdx.x;        // 0..16383
    if (gt == 0) out[OUT_LOSS] = 0.f;
    if (gt < 256) out[OUT_SUM + gt] = 0.f;
    // embedding passthrough: 4 floats/thread (OUT_EMB is odd -> scalar stores)
    {
        float4 v = *(const float4*)(emb + (size_t)gt * 4);
        float* o = out + OUT_EMB + (size_t)gt * 4;
        o[0] = v.x; o[1] = v.y; o[2] = v.z; o[3] = v.w;
    }
    // fragment swizzle: 8192 threads, one (code, 8-chan octet) each
    if (gt < 8192) {
        int k = gt >> 3, oct = gt & 7;
        int ch = k >> 7, mt = (k >> 4) & 7, row = k & 15;
        int s = oct >> 2, g = oct & 3;              // c = oct*8+i
        const float* e = emb + (size_t)k * CDIM + oct * 8;
        char* rec = ws + (size_t)ch * REC_BYTES;
        _Float16* hi = (_Float16*)rec + (size_t)(mt * 2 + s) * 512 + ((g << 4) | row) * 8;
        _Float16* lo = hi + 8192;
        float s2 = 0.f;
        half8 hv, lv;
#pragma unroll
        for (int i = 0; i < 8; ++i) {
            float v = e[i];
            s2 = fmaf(v, v, s2);
            _Float16 h = (_Float16)v;
            hv[i] = h;
            lv[i] = (_Float16)(v - (float)h);
        }
        *(half8*)hi = hv;
        *(half8*)lo = lv;
        // reduce s2 over the 8-lane octet group (same wave: 8 codes per 64 lanes)
        s2 += __shfl_xor(s2, 1);
        s2 += __shfl_xor(s2, 2);
        s2 += __shfl_xor(s2, 4);
        if (oct == 0) ((float*)(rec + 32768))[k & 127] = -0.5f * s2;
    }
}

// ---- main VQ kernel ----
// Block: 256 thr = 4 waves, 64 positions (4 N-tiles of 16 per wave).
// mt-interleaved K-split: wave wv scans gmt = wv, wv+4, ..., wv+60 -> all waves
// walk the same chunks (L1 reuse). 2-deep register prefetch hides L2 latency.
// Score = x.e - 0.5||e||^2 (C-init), argmax == argmin distance. No main-loop barriers.
__global__ __launch_bounds__(256, 3) void vq_kernel(
        const float* __restrict__ in, const float* __restrict__ emb,
        const char* __restrict__ wsA, float* __restrict__ out) {
    __shared__ float xl[CDIM * 65];        // x tile [c][pos], pitch 65 (16640 B)
    __shared__ float redS[4][4][16];       // wave, tile, col
    __shared__ int   redK[4][4][16];
    __shared__ int   kwin[BPOS];

    const int tid  = threadIdx.x;
    const int lane = tid & 63, wv = tid >> 6;
    const int g = lane >> 4, col = lane & 15;
    const int p0 = blockIdx.x * BPOS;
    const int b  = p0 >> 15;               // 64-pos tile never straddles batch
    const int s0 = p0 & 32767;
    const float* xin = in + (size_t)b * (CDIM * SPATIAL) + s0;

    // phase A: x tile -> LDS f32 [c][pos]
    {
        int p = tid & 63, cq = tid >> 6;
#pragma unroll
        for (int j = 0; j < 16; ++j) {
            int c = cq * 16 + j;
            xl[c * 65 + p] = xin[(size_t)c * SPATIAL + p];
        }
    }
    __syncthreads();

    // phase B: per-wave B-fragments (positions) hi/lo fp16
    half8 bh[4][2], bl[4][2];
#pragma unroll
    for (int t = 0; t < 4; ++t)
#pragma unroll
        for (int s = 0; s < 2; ++s) {
            int p = t * 16 + col;
#pragma unroll
            for (int i = 0; i < 8; ++i) {
                int c = s * 32 + g * 8 + i;
                float v = xl[c * 65 + p];
                _Float16 h = (_Float16)v;
                bh[t][s][i] = h;
                bl[t][s][i] = (_Float16)(v - (float)h);
            }
        }

    float best[4][4];
    int   bmt[4][4];                       // stores winning gmt (0..63)
#pragma unroll
    for (int t = 0; t < 4; ++t)
#pragma unroll
        for (int r = 0; r < 4; ++r) { best[t][r] = -3.402823466e38f; bmt[t][r] = 0; }

#define LOADF(IT, H0, H1, L0, L1, EI) do {                                   \
        int gmt_ = wv + 4 * (IT);                                            \
        const char* rec_ = wsA + (size_t)(gmt_ >> 3) * REC_BYTES;            \
        int mt_ = gmt_ & 7;                                                  \
        const char* hp_ = rec_ + mt_ * 2048 + (size_t)lane * 16;             \
        H0 = *(const half8*)(hp_);                                           \
        H1 = *(const half8*)(hp_ + 1024);                                    \
        L0 = *(const half8*)(hp_ + 16384);                                   \
        L1 = *(const half8*)(hp_ + 17408);                                   \
        EI = *(const f32x4*)(rec_ + 32768 + mt_ * 64 + g * 16);              \
    } while (0)

#define CONSUME(IT, H0, H1, L0, L1, EI) do {                                 \
        int gmt_ = wv + 4 * (IT);                                            \
        _Pragma("unroll")                                                    \
        for (int t = 0; t < 4; ++t) {                                        \
            f32x4 a = EI;                                                    \
            a = __builtin_amdgcn_mfma_f32_16x16x32_f16(H0, bh[t][0], a, 0, 0, 0); \
            a = __builtin_amdgcn_mfma_f32_16x16x32_f16(H1, bh[t][1], a, 0, 0, 0); \
            a = __builtin_amdgcn_mfma_f32_16x16x32_f16(H0, bl[t][0], a, 0, 0, 0); \
            a = __builtin_amdgcn_mfma_f32_16x16x32_f16(H1, bl[t][1], a, 0, 0, 0); \
            a = __builtin_amdgcn_mfma_f32_16x16x32_f16(L0, bh[t][0], a, 0, 0, 0); \
            a = __builtin_amdgcn_mfma_f32_16x16x32_f16(L1, bh[t][1], a, 0, 0, 0); \
            _Pragma("unroll")                                                \
            for (int r = 0; r < 4; ++r)                                      \
                if (a[r] > best[t][r]) { best[t][r] = a[r]; bmt[t][r] = gmt_; } \
        }                                                                    \
    } while (0)

    // 16 iterations, 2-deep register prefetch (A/B named sets, static indexing)
    half8 Ah0, Ah1, Al0, Al1, Bh0, Bh1, Bl0, Bl1;
    f32x4 Aei, Bei;
    LOADF(0, Ah0, Ah1, Al0, Al1, Aei);
#pragma unroll
    for (int it = 0; it < 16; it += 2) {
        LOADF(it + 1, Bh0, Bh1, Bl0, Bl1, Bei);
        CONSUME(it, Ah0, Ah1, Al0, Al1, Aei);
        if (it + 2 < 16) LOADF(it + 2, Ah0, Ah1, Al0, Al1, Aei);
        CONSUME(it + 1, Bh0, Bh1, Bl0, Bl1, Bei);
    }
#undef LOADF
#undef CONSUME

    // per-wave lex-reduce (score desc, k asc) -> LDS
#pragma unroll
    for (int t = 0; t < 4; ++t) {
        float bs = best[t][0];
        int   bk = bmt[t][0] * 16 + g * 4 + 0;
#pragma unroll
        for (int r = 1; r < 4; ++r) {
            float sc = best[t][r];
            int   k  = bmt[t][r] * 16 + g * 4 + r;
            if (sc > bs || (sc == bs && k < bk)) { bs = sc; bk = k; }
        }
#pragma unroll
        for (int m = 16; m <= 32; m <<= 1) {
            float os = __shfl_xor(bs, m);
            int   ok = __shfl_xor(bk, m);
            if (os > bs || (os == bs && ok < bk)) { bs = os; bk = ok; }
        }
        if (g == 0) { redS[wv][t][col] = bs; redK[wv][t][col] = bk; }
    }
    __syncthreads();

    // cross-wave reduce (wave 0), write indices coalesced, publish winners
    if (wv == 0) {
        int t = lane >> 4, c2 = lane & 15;
        float bs = redS[0][t][c2];
        int   bk = redK[0][t][c2];
#pragma unroll
        for (int w = 1; w < 4; ++w) {
            float sc = redS[w][t][c2];
            int   k  = redK[w][t][c2];
            if (sc > bs || (sc == bs && k < bk)) { bs = sc; bk = k; }
        }
        kwin[lane] = bk;
        out[OUT_IDX + p0 + lane] = (float)bk;
    }
    __syncthreads();

    // epilogue: coalesced q stores (lane = position), exact f32 x from LDS
    float lsum = 0.f;
    {
        int p = tid & 63, cq = tid >> 6;
        int kk = kwin[p];
        const float* eb = emb + (size_t)kk * CDIM;     // L1/L2 gather
        float* q = out + OUT_Q + (size_t)b * (CDIM * SPATIAL) + s0;
#pragma unroll
        for (int j = 0; j < 16; ++j) {
            int c = cq * 16 + j;
            float e = eb[c];
            float x = xl[c * 65 + p];
            float d = e - x;                           // stop_grad(q - x)
            lsum = fmaf(d, d, lsum);
            q[(size_t)c * SPATIAL + p] = x + d;        // straight-through
        }
    }
#pragma unroll
    for (int off = 32; off > 0; off >>= 1) lsum += __shfl_down(lsum, off);
    if (lane == 0) redS[wv][0][0] = lsum;
    __syncthreads();
    if (tid == 0) {
        float t = redS[0][0][0] + redS[1][0][0] + redS[2][0][0] + redS[3][0][0];
        atomicAdd(out + OUT_LOSS, t * (0.25f / (float)NEL));
    }
}

extern "C" void kernel_launch(void* const* d_in, const int* in_sizes, int n_in,
                              void* d_out, int out_size, void* d_ws, size_t ws_size,
                              hipStream_t stream) {
    const float* in  = (const float*)d_in[0];   // [2,64,32,32,32] f32
    const float* emb = (const float*)d_in[1];   // [1024,64] f32
    float* out = (float*)d_out;
    char*  ws  = (char*)d_ws;                   // 266,240 B used

    prep_emb<<<64, 256, 0, stream>>>(emb, ws, out);
    vq_kernel<<<NPOS / BPOS, 256, 0, stream>>>(in, emb, ws, out);
}

// Round 5
// 49.574 us; speedup vs baseline: 1.9130x; 1.9130x over previous
//
#include <hip/hip_runtime.h>
#include <stdint.h>

#define KCODES  1024
#define CDIM    64
#define SPATIAL 32768
#define NPOS    65536
#define NEL     4194304

// d_out layout (floats), outputs concatenated in reference return order
#define OUT_Q    0
#define OUT_LOSS 4194304
#define OUT_IDX  4194305
#define OUT_SUM  4259841
#define OUT_EMB  4260097

// ws: 8 chunks x {hi frags 16KB | lo frags 16KB | -0.5*||e||^2 512B}
#define REC_BYTES 33280
#define BPOS 64            // positions per block

typedef _Float16 half8 __attribute__((ext_vector_type(8)));
typedef float    f32x4 __attribute__((ext_vector_type(4)));

// ---- prep: fragment-swizzle codebook, zero loss/sum, emb passthrough (64 blocks) ----
__global__ void prep_emb(const float* __restrict__ emb, char* __restrict__ ws,
                         float* __restrict__ out) {
    int gt = blockIdx.x * 256 + threadIdx.x;        // 0..16383
    if (gt == 0) out[OUT_LOSS] = 0.f;
    if (gt < 256) out[OUT_SUM + gt] = 0.f;
    // embedding passthrough: 4 floats/thread (OUT_EMB is odd -> scalar stores)
    {
        float4 v = *(const float4*)(emb + (size_t)gt * 4);
        float* o = out + OUT_EMB + (size_t)gt * 4;
        o[0] = v.x; o[1] = v.y; o[2] = v.z; o[3] = v.w;
    }
    // fragment swizzle: 8192 threads, one (code, 8-chan octet) each
    if (gt < 8192) {
        int k = gt >> 3, oct = gt & 7;
        int ch = k >> 7, mt = (k >> 4) & 7, row = k & 15;
        int s = oct >> 2, g = oct & 3;              // c = oct*8+i
        const float* e = emb + (size_t)k * CDIM + oct * 8;
        char* rec = ws + (size_t)ch * REC_BYTES;
        _Float16* hi = (_Float16*)rec + (size_t)(mt * 2 + s) * 512 + ((g << 4) | row) * 8;
        _Float16* lo = hi + 8192;
        float s2 = 0.f;
        half8 hv, lv;
#pragma unroll
        for (int i = 0; i < 8; ++i) {
            float v = e[i];
            s2 = fmaf(v, v, s2);
            _Float16 h = (_Float16)v;
            hv[i] = h;
            lv[i] = (_Float16)(v - (float)h);
        }
        *(half8*)hi = hv;
        *(half8*)lo = lv;
        // reduce s2 over the 8-lane octet group (same wave: 8 codes per 64 lanes)
        s2 += __shfl_xor(s2, 1);
        s2 += __shfl_xor(s2, 2);
        s2 += __shfl_xor(s2, 4);
        if (oct == 0) ((float*)(rec + 32768))[k & 127] = -0.5f * s2;
    }
}

// ---- main VQ kernel ----
// Block: 256 thr = 4 waves, 64 positions (4 N-tiles of 16 per wave).
// mt-INTERLEAVED K-split: wave wv scans gmt = wv, wv+4, ..., wv+60 so all waves
// on a CU walk the same 4KB fragment sets in near-lockstep -> L1-broadcast hits,
// L2 traffic cut ~16x vs chunked split. NO register prefetch (R4 spilled).
// Score = x.e - 0.5||e||^2 (C-init), argmax == argmin distance. No main-loop barriers.
__global__ __launch_bounds__(256, 3) void vq_kernel(
        const float* __restrict__ in, const float* __restrict__ emb,
        const char* __restrict__ wsA, float* __restrict__ out) {
    __shared__ float xl[CDIM * 65];        // x tile [c][pos], pitch 65 (16640 B)
    __shared__ float redS[4][4][16];       // wave, tile, col
    __shared__ int   redK[4][4][16];
    __shared__ int   kwin[BPOS];

    const int tid  = threadIdx.x;
    const int lane = tid & 63, wv = tid >> 6;
    const int g = lane >> 4, col = lane & 15;
    const int p0 = blockIdx.x * BPOS;
    const int b  = p0 >> 15;               // 64-pos tile never straddles batch
    const int s0 = p0 & 32767;
    const float* xin = in + (size_t)b * (CDIM * SPATIAL) + s0;

    // phase A: x tile -> LDS f32 [c][pos]
    {
        int p = tid & 63, cq = tid >> 6;
#pragma unroll
        for (int j = 0; j < 16; ++j) {
            int c = cq * 16 + j;
            xl[c * 65 + p] = xin[(size_t)c * SPATIAL + p];
        }
    }
    __syncthreads();

    // phase B: per-wave B-fragments (positions) hi/lo fp16
    half8 bh[4][2], bl[4][2];
#pragma unroll
    for (int t = 0; t < 4; ++t)
#pragma unroll
        for (int s = 0; s < 2; ++s) {
            int p = t * 16 + col;
#pragma unroll
            for (int i = 0; i < 8; ++i) {
                int c = s * 32 + g * 8 + i;
                float v = xl[c * 65 + p];
                _Float16 h = (_Float16)v;
                bh[t][s][i] = h;
                bl[t][s][i] = (_Float16)(v - (float)h);
            }
        }

    float best[4][4];
    int   bmt[4][4];                       // stores winning gmt (0..63)
#pragma unroll
    for (int t = 0; t < 4; ++t)
#pragma unroll
        for (int r = 0; r < 4; ++r) { best[t][r] = -3.402823466e38f; bmt[t][r] = 0; }

    // main loop: 16 interleaved mt-tiles, plain loads (TLP + L1 hits hide latency)
    for (int o = 0; o < 4; ++o) {
#pragma unroll
        for (int ii = 0; ii < 4; ++ii) {
            int gmt = wv + 4 * (o * 4 + ii);
            const char* rec = wsA + (size_t)(gmt >> 3) * REC_BYTES;
            int mt = gmt & 7;
            const char* hp = rec + mt * 2048 + (size_t)lane * 16;
            half8 ah0 = *(const half8*)(hp);
            half8 ah1 = *(const half8*)(hp + 1024);
            half8 al0 = *(const half8*)(hp + 16384);
            half8 al1 = *(const half8*)(hp + 17408);
            f32x4 ei  = *(const f32x4*)(rec + 32768 + mt * 64 + g * 16);
#pragma unroll
            for (int t = 0; t < 4; ++t) {
                f32x4 a = ei;
                a = __builtin_amdgcn_mfma_f32_16x16x32_f16(ah0, bh[t][0], a, 0, 0, 0);
                a = __builtin_amdgcn_mfma_f32_16x16x32_f16(ah1, bh[t][1], a, 0, 0, 0);
                a = __builtin_amdgcn_mfma_f32_16x16x32_f16(ah0, bl[t][0], a, 0, 0, 0);
                a = __builtin_amdgcn_mfma_f32_16x16x32_f16(ah1, bl[t][1], a, 0, 0, 0);
                a = __builtin_amdgcn_mfma_f32_16x16x32_f16(al0, bh[t][0], a, 0, 0, 0);
                a = __builtin_amdgcn_mfma_f32_16x16x32_f16(al1, bh[t][1], a, 0, 0, 0);
#pragma unroll
                for (int r = 0; r < 4; ++r)
                    if (a[r] > best[t][r]) { best[t][r] = a[r]; bmt[t][r] = gmt; }
            }
        }
    }

    // per-wave lex-reduce (score desc, k asc) -> LDS
#pragma unroll
    for (int t = 0; t < 4; ++t) {
        float bs = best[t][0];
        int   bk = bmt[t][0] * 16 + g * 4 + 0;
#pragma unroll
        for (int r = 1; r < 4; ++r) {
            float sc = best[t][r];
            int   k  = bmt[t][r] * 16 + g * 4 + r;
            if (sc > bs || (sc == bs && k < bk)) { bs = sc; bk = k; }
        }
#pragma unroll
        for (int m = 16; m <= 32; m <<= 1) {
            float os = __shfl_xor(bs, m);
            int   ok = __shfl_xor(bk, m);
            if (os > bs || (os == bs && ok < bk)) { bs = os; bk = ok; }
        }
        if (g == 0) { redS[wv][t][col] = bs; redK[wv][t][col] = bk; }
    }
    __syncthreads();

    // cross-wave reduce (wave 0), write indices coalesced, publish winners
    if (wv == 0) {
        int t = lane >> 4, c2 = lane & 15;
        float bs = redS[0][t][c2];
        int   bk = redK[0][t][c2];
#pragma unroll
        for (int w = 1; w < 4; ++w) {
            float sc = redS[w][t][c2];
            int   k  = redK[w][t][c2];
            if (sc > bs || (sc == bs && k < bk)) { bs = sc; bk = k; }
        }
        kwin[lane] = bk;
        out[OUT_IDX + p0 + lane] = (float)bk;
    }
    __syncthreads();

    // epilogue: coalesced q stores (lane = position), exact f32 x from LDS
    float lsum = 0.f;
    {
        int p = tid & 63, cq = tid >> 6;
        int kk = kwin[p];
        const float* eb = emb + (size_t)kk * CDIM;     // L1/L2 gather
        float* q = out + OUT_Q + (size_t)b * (CDIM * SPATIAL) + s0;
#pragma unroll
        for (int j = 0; j < 16; ++j) {
            int c = cq * 16 + j;
            float e = eb[c];
            float x = xl[c * 65 + p];
            float d = e - x;                           // stop_grad(q - x)
            lsum = fmaf(d, d, lsum);
            q[(size_t)c * SPATIAL + p] = x + d;        // straight-through
        }
    }
#pragma unroll
    for (int off = 32; off > 0; off >>= 1) lsum += __shfl_down(lsum, off);
    if (lane == 0) redS[wv][0][0] = lsum;
    __syncthreads();
    if (tid == 0) {
        float t = redS[0][0][0] + redS[1][0][0] + redS[2][0][0] + redS[3][0][0];
        atomicAdd(out + OUT_LOSS, t * (0.25f / (float)NEL));
    }
}

extern "C" void kernel_launch(void* const* d_in, const int* in_sizes, int n_in,
                              void* d_out, int out_size, void* d_ws, size_t ws_size,
                              hipStream_t stream) {
    const float* in  = (const float*)d_in[0];   // [2,64,32,32,32] f32
    const float* emb = (const float*)d_in[1];   // [1024,64] f32
    float* out = (float*)d_out;
    char*  ws  = (char*)d_ws;                   // 266,240 B used

    prep_emb<<<64, 256, 0, stream>>>(emb, ws, out);
    vq_kernel<<<NPOS / BPOS, 256, 0, stream>>>(in, emb, ws, out);
}